// Round 19
// baseline (349.953 us; speedup 1.0000x reference)
//
#include <hip/hip_runtime.h>
#include <hip/hip_bf16.h>

// ColorINN R19: next rung of the occupancy ladder. N=4 (launch_bounds(256,4),
// VGPR budget 256/4=64) enabled by halving per-wave slots 4->2 (wave=32 pts,
// block=128 pts): bfr1 shrinks 64->32 VGPRs, accumulators 32->16. Fragment
// loads per point double but hit L1/L2 on the idle VMEM pipe. Grid 4096 =
// 4 blocks/CU x 4 exact phases. Body otherwise verbatim R18.

#define MEMBAR() asm volatile("" ::: "memory")

typedef float    f32x4 __attribute__((ext_vector_type(4)));
typedef short    s16x4 __attribute__((ext_vector_type(4)));
typedef int      i32x4 __attribute__((ext_vector_type(4)));
typedef _Float16 h16x2 __attribute__((ext_vector_type(2)));
typedef _Float16 h16x8 __attribute__((ext_vector_type(8)));

#define MFMA(a,b,c) __builtin_amdgcn_mfma_f32_16x16x32_f16((a),(b),(c),0,0,0)

#define LBYTES 46080
// per-layer ws layout (validated R14/R15): A2 frag f=mf*4+kc @ f*1024 (32KB);
// A1 mf @ (32+mf)*1024; A3 kc @ (40+kc)*1024; smalls f32 @ 45056:
// [0..15]=PS [16..19]=PB [20..23]=0.1*b3 [24..151]=b2

__device__ __forceinline__ h16x2 pkrtz(float a, float b){
  auto t = __builtin_amdgcn_cvt_pkrtz(a, b);
  h16x2 r; __builtin_memcpy(&r, &t, 4); return r;
}
__device__ __forceinline__ unsigned pkh(float a, float b){
  auto t = __builtin_amdgcn_cvt_pkrtz(a, b);
  unsigned r; __builtin_memcpy(&r, &t, 4); return r;
}

// packed GELU: y = x * (0.5 + xc*D(xc^2)), xc = clamp(x,±3.75)/4, deg-9 odd.
__device__ __forceinline__ h16x2 gelu_pk(h16x2 x){
  const h16x2 Q   = {(_Float16)0.25f,      (_Float16)0.25f};
  const h16x2 CLO = {(_Float16)-0.9375f,   (_Float16)-0.9375f};
  const h16x2 CHI = {(_Float16)0.9375f,    (_Float16)0.9375f};
  const h16x2 D4  = {(_Float16)2.639031f,  (_Float16)2.639031f};
  const h16x2 D3  = {(_Float16)-6.920503f, (_Float16)-6.920503f};
  const h16x2 D2  = {(_Float16)7.180759f,  (_Float16)7.180759f};
  const h16x2 D1  = {(_Float16)-3.960064f, (_Float16)-3.960064f};
  const h16x2 D0  = {(_Float16)1.590628f,  (_Float16)1.590628f};
  const h16x2 H   = {(_Float16)0.5f,       (_Float16)0.5f};
  h16x2 xs = x * Q;
  xs = __builtin_elementwise_max(xs, CLO);
  xs = __builtin_elementwise_min(xs, CHI);
  h16x2 t = xs * xs;
  h16x2 s = t*D4 + D3;
  s = s*t + D2;
  s = s*t + D1;
  s = s*t + D0;
  h16x2 phi = xs*s + H;
  return x * phi;
}

__device__ __forceinline__ void gelu4(const f32x4 c, unsigned& w0, unsigned& w1){
  h16x2 p0 = gelu_pk(pkrtz(c[0], c[1]));
  h16x2 p1 = gelu_pk(pkrtz(c[2], c[3]));
  __builtin_memcpy(&w0, &p0, 4);
  __builtin_memcpy(&w1, &p1, 4);
}

// ---------------- prepack (verbatim — validated) ----------------
__global__ void prepack(const float* __restrict__ W1, const float* __restrict__ b1,
                        const float* __restrict__ W2, const float* __restrict__ b2,
                        const float* __restrict__ W3, const float* __restrict__ b3,
                        const float* __restrict__ gg, const float* __restrict__ off,
                        const float* __restrict__ Pm, unsigned char* __restrict__ ws)
{
  int t = blockIdx.x * 256 + threadIdx.x;
  if (t >= 8 * 45 * 64) return;
  int l    = t / (45 * 64);
  int rem  = t % (45 * 64);
  int f    = rem / 64;
  int lane = rem % 64;
  int p = lane & 15, g = lane >> 4;
  unsigned char* lb = ws + l * LBYTES;

  if (f < 32) {
    int mf = f >> 2, kc = f & 3;
    const float* rw = W2 + l*16384 + (16*mf + p)*128 + 32*kc + 8*g;
    f32x4 u0 = *(const f32x4*)rw;
    f32x4 u1 = *(const f32x4*)(rw + 4);
    i32x4 w;
    w[0] = (int)pkh(u0[0], u0[1]); w[1] = (int)pkh(u0[2], u0[3]);
    w[2] = (int)pkh(u1[0], u1[1]); w[3] = (int)pkh(u1[2], u1[3]);
    *(i32x4*)(lb + f*1024 + lane*16) = w;
  } else if (f < 40) {
    int mf = f - 32;
    i32x4 w = (i32x4){0,0,0,0};
    if (g == 0) {
      int row = 16*mf + p;
      w[0] = (int)pkh(W1[l*256 + row*2 + 0], W1[l*256 + row*2 + 1]);
      w[1] = (int)pkh(b1[l*128 + row], 0.f);
    }
    *(i32x4*)(lb + f*1024 + lane*16) = w;
  } else if (f < 44) {
    int kc = f - 40;
    i32x4 w = (i32x4){0,0,0,0};
    if (p < 4) {
      const float* rw = W3 + l*512 + p*128 + 8*g + 32*kc;
      f32x4 u0 = *(const f32x4*)(rw);
      f32x4 u1 = *(const f32x4*)(rw + 4);
      w[0] = (int)pkh(0.1f*u0[0], 0.1f*u0[1]); w[1] = (int)pkh(0.1f*u0[2], 0.1f*u0[3]);
      w[2] = (int)pkh(0.1f*u1[0], 0.1f*u1[1]); w[3] = (int)pkh(0.1f*u1[2], 0.1f*u1[3]);
    }
    *(i32x4*)(lb + f*1024 + lane*16) = w;
  } else {
    float* sm = (float*)(lb + 45056);
    if (lane < 16) {
      int j = lane & 3;
      float scl = 0.2f * log1pf(expf(0.5f * gg[l*4 + j]));
      sm[lane] = Pm[l*16 + lane] * scl;
    } else if (lane < 20) {
      int i = lane - 16; float acc = 0.f;
      #pragma unroll
      for (int j = 0; j < 4; ++j) acc += Pm[l*16 + i*4 + j] * off[l*4 + j];
      sm[16 + i] = acc;
    } else if (lane < 24) {
      sm[lane] = 0.1f * b3[l*4 + (lane - 20)];
    }
    sm[24 + lane]      = b2[l*128 + lane];
    sm[24 + 64 + lane] = b2[l*128 + 64 + lane];
  }
}

// ---------------- main kernel ----------------
__global__ __launch_bounds__(256, 4) void inn_main(
    const float* __restrict__ XYZ,
    const unsigned char* __restrict__ ws,
    float* __restrict__ outp)
{
  // per wave: h buffer 4352B + xs state 512B = 4864B; 4 waves = 19456B
  __shared__ __align__(16) unsigned char lds[4*4864];

  const int tid  = threadIdx.x;
  const int wid  = tid >> 6;
  const int lane = tid & 63;
  const int p    = lane & 15;
  const int g    = lane >> 4;
  unsigned char* hb = lds + wid*4864;
  float* xs = (float*)(hb + 4352);
  const long base_pt = (long)blockIdx.x*128 + wid*32;
  const f32x4 z4 = {0.f,0.f,0.f,0.f};
  const h16x8 zh = {(_Float16)0,(_Float16)0,(_Float16)0,(_Float16)0,
                    (_Float16)0,(_Float16)0,(_Float16)0,(_Float16)0};
  const unsigned loff = (unsigned)lane * 16u;

  if (lane < 16) {
    for (int s = 0; s < 2; ++s) {
      long pt = base_pt + s*16 + p;
      f32x4 v;
      v[0]=XYZ[pt*3+0]; v[1]=XYZ[pt*3+1]; v[2]=XYZ[pt*3+2]; v[3]=0.f;
      *(f32x4*)&xs[(s*16+p)*4] = v;
    }
  }
  MEMBAR();

  for (int l = 0; l < 8; ++l) {
    const unsigned char* lb = ws + l * LBYTES;
    const float* sm = (const float*)(lb + 45056);
    f32x4 b3v = z4;
    if (g == 0) b3v = *(const f32x4*)(sm + 20);

    // ---- one 2-slot group per wave (32 points) ----
    h16x8 bx[2];
    #pragma unroll
    for (int t = 0; t < 2; ++t) {
      f32x4 xv = *(const f32x4*)&xs[(t*16+p)*4];
      h16x8 b = zh;
      if (g == 0) { b[0]=(_Float16)xv[0]; b[1]=(_Float16)xv[1]; b[2]=(_Float16)1.0f; }
      bx[t] = b;
    }
    h16x8 bfr1[4][2];   // [kc(=mfp)][slot]
    #pragma unroll
    for (int mfp = 0; mfp < 4; ++mfp) {
      h16x8 a1a = *(const h16x8*)(lb + (32 + 2*mfp)*1024 + loff);
      h16x8 a1b = *(const h16x8*)(lb + (33 + 2*mfp)*1024 + loff);
      f32x4 c1a[2], c1b[2];
      #pragma unroll
      for (int t = 0; t < 2; ++t) {
        c1a[t] = MFMA(a1a, bx[t], z4);
        c1b[t] = MFMA(a1b, bx[t], z4);
      }
      MEMBAR();
      #pragma unroll
      for (int t = 0; t < 2; ++t) {
        i32x4 w; unsigned w0,w1,w2,w3;
        gelu4(c1a[t], w0, w1); gelu4(c1b[t], w2, w3);
        w[0]=(int)w0; w[1]=(int)w1; w[2]=(int)w2; w[3]=(int)w3;
        *(i32x4*)(hb + p*272 + (4*t + g)*16) = w;
      }
      MEMBAR();
      #pragma unroll
      for (int t = 0; t < 2; ++t) {
        const unsigned char* ra = hb + p*272 + (4*t + 2*(g & 1))*16 + (g >> 1)*8;
        s16x4 lo = *(const s16x4*)(ra);
        s16x4 hi = *(const s16x4*)(ra + 16);
        h16x8 b;
        __builtin_memcpy(&b, &lo, 8);
        __builtin_memcpy(((char*)&b)+8, &hi, 8);
        bfr1[mfp][t] = b;
      }
      MEMBAR();
    }

    // ---- G2+G3 fused per mf-pair ----
    f32x4 c3[2];
    #pragma unroll
    for (int t = 0; t < 2; ++t) c3[t] = b3v;
    #pragma unroll
    for (int mfp = 0; mfp < 4; ++mfp) {
      f32x4 bv0 = *(const f32x4*)(sm + 24 + 16*(2*mfp)   + 4*g);
      f32x4 bv1 = *(const f32x4*)(sm + 24 + 16*(2*mfp+1) + 4*g);
      f32x4 c2a[2], c2b[2];
      #pragma unroll
      for (int t = 0; t < 2; ++t) { c2a[t] = bv0; c2b[t] = bv1; }
      #pragma unroll
      for (int kc = 0; kc < 4; ++kc) {
        h16x8 af0 = *(const h16x8*)(lb + ((2*mfp)*4   + kc)*1024 + loff);
        h16x8 af1 = *(const h16x8*)(lb + ((2*mfp+1)*4 + kc)*1024 + loff);
        #pragma unroll
        for (int t = 0; t < 2; ++t) {
          c2a[t] = MFMA(af0, bfr1[kc][t], c2a[t]);
          c2b[t] = MFMA(af1, bfr1[kc][t], c2b[t]);
        }
      }
      h16x8 a3 = *(const h16x8*)(lb + (40 + mfp)*1024 + loff);
      MEMBAR();
      #pragma unroll
      for (int t = 0; t < 2; ++t) {
        i32x4 w; unsigned w0,w1,w2,w3;
        gelu4(c2a[t], w0, w1); gelu4(c2b[t], w2, w3);
        w[0]=(int)w0; w[1]=(int)w1; w[2]=(int)w2; w[3]=(int)w3;
        *(i32x4*)(hb + p*272 + (4*t + g)*16) = w;
      }
      MEMBAR();
      #pragma unroll
      for (int t = 0; t < 2; ++t) {
        const unsigned char* ra = hb + p*272 + (4*t + 2*(g & 1))*16 + (g >> 1)*8;
        s16x4 lo = *(const s16x4*)(ra);
        s16x4 hi = *(const s16x4*)(ra + 16);
        h16x8 b;
        __builtin_memcpy(&b, &lo, 8);
        __builtin_memcpy(((char*)&b)+8, &hi, 8);
        c3[t] = MFMA(a3, b, c3[t]);
      }
      MEMBAR();
    }

    // ---- tails ----
    f32x4 ps0 = *(const f32x4*)(sm + 0);
    f32x4 ps1 = *(const f32x4*)(sm + 4);
    f32x4 ps2 = *(const f32x4*)(sm + 8);
    f32x4 ps3 = *(const f32x4*)(sm + 12);
    f32x4 pb  = *(const f32x4*)(sm + 16);
    int addr = p << 2;
    #pragma unroll
    for (int t = 0; t < 2; ++t) {
      f32x4 xv = *(const f32x4*)&xs[(t*16+p)*4];
      float a0 = __int_as_float(__builtin_amdgcn_ds_bpermute(addr, __float_as_int(c3[t][0])));
      float a1 = __int_as_float(__builtin_amdgcn_ds_bpermute(addr, __float_as_int(c3[t][1])));
      float a2 = __int_as_float(__builtin_amdgcn_ds_bpermute(addr, __float_as_int(c3[t][2])));
      float a3f= __int_as_float(__builtin_amdgcn_ds_bpermute(addr, __float_as_int(c3[t][3])));
      float t0 = __builtin_amdgcn_rcpf(1.f + __builtin_amdgcn_exp2f(2.8853901f * a0));
      float t1 = __builtin_amdgcn_rcpf(1.f + __builtin_amdgcn_exp2f(2.8853901f * a1));
      float e0 = __builtin_amdgcn_exp2f(__builtin_fmaf(-5.7707802f, t0, 2.8853901f));
      float e1 = __builtin_amdgcn_exp2f(__builtin_fmaf(-5.7707802f, t1, 2.8853901f));
      float v2 = __builtin_fmaf(xv[2], e0, a2);
      float v3 = __builtin_fmaf(xv[3], e1, a3f);
      f32x4 y;
      y[0] = __builtin_fmaf(ps0[0], xv[0], __builtin_fmaf(ps0[1], xv[1],
             __builtin_fmaf(ps0[2], v2, __builtin_fmaf(ps0[3], v3, pb[0]))));
      y[1] = __builtin_fmaf(ps1[0], xv[0], __builtin_fmaf(ps1[1], xv[1],
             __builtin_fmaf(ps1[2], v2, __builtin_fmaf(ps1[3], v3, pb[1]))));
      y[2] = __builtin_fmaf(ps2[0], xv[0], __builtin_fmaf(ps2[1], xv[1],
             __builtin_fmaf(ps2[2], v2, __builtin_fmaf(ps2[3], v3, pb[2]))));
      y[3] = __builtin_fmaf(ps3[0], xv[0], __builtin_fmaf(ps3[1], xv[1],
             __builtin_fmaf(ps3[2], v2, __builtin_fmaf(ps3[3], v3, pb[3]))));
      if (g == 0) *(f32x4*)&xs[(t*16+p)*4] = y;
    }
    MEMBAR();
  }

  if (lane < 16) {
    for (int s = 0; s < 2; ++s) {
      long pt = base_pt + s*16 + p;
      f32x4 xv = *(const f32x4*)&xs[(s*16+p)*4];
      outp[pt*3+0] = xv[0];
      outp[pt*3+1] = xv[1];
      outp[pt*3+2] = xv[2];
    }
  }
}

extern "C" void kernel_launch(void* const* d_in, const int* in_sizes, int n_in,
                              void* d_out, int out_size, void* d_ws, size_t ws_size,
                              hipStream_t stream)
{
  const float* XYZ = (const float*)d_in[0];
  const float* W1  = (const float*)d_in[1];
  const float* b1  = (const float*)d_in[2];
  const float* W2  = (const float*)d_in[3];
  const float* b2  = (const float*)d_in[4];
  const float* W3  = (const float*)d_in[5];
  const float* b3  = (const float*)d_in[6];
  const float* g   = (const float*)d_in[7];
  const float* off = (const float*)d_in[8];
  const float* P   = (const float*)d_in[9];
  unsigned char* ws = (unsigned char*)d_ws;

  prepack<<<90, 256, 0, stream>>>(W1, b1, W2, b2, W3, b3, g, off, P, ws);

  int Bn = in_sizes[0] / 3;          // 524288
  int nblocks = Bn / 128;            // 4096 exact
  inn_main<<<nblocks, 256, 0, stream>>>(XYZ, ws, (float*)d_out);
}

// Round 20
// 330.917 us; speedup vs baseline: 1.0575x; 1.0575x over previous
//
#include <hip/hip_runtime.h>
#include <hip/hip_bf16.h>

// ColorINN R20: R18 structure (best: 325us) with the compiler-barrier tax
// removed. The ~20 full MEMBARs/layer existed only to stop TBAA reordering of
// LDS h-buffer writes (i32x4) vs reads (s16x4). Fix: may_alias on both LDS
// access types (forces compiler-preserved LDS ordering; per-lane ranges
// overlap for some g in every true dep, so addr-AA can't reorder either) and
// DELETE the MEMBARs. Global ws loads (as1) still hoist freely across LDS
// (as3) by address-space AA -> fragment loads pipeline across the layer.

#define MEMBAR() asm volatile("" ::: "memory")

typedef float    f32x4 __attribute__((ext_vector_type(4)));
typedef short    s16x4 __attribute__((ext_vector_type(4), may_alias));
typedef int      i32x4 __attribute__((ext_vector_type(4), may_alias));
typedef _Float16 h16x2 __attribute__((ext_vector_type(2)));
typedef _Float16 h16x8 __attribute__((ext_vector_type(8)));

#define MFMA(a,b,c) __builtin_amdgcn_mfma_f32_16x16x32_f16((a),(b),(c),0,0,0)

#define LBYTES 46080
// per-layer ws layout (validated R14/R15): A2 frag f=mf*4+kc @ f*1024 (32KB);
// A1 mf @ (32+mf)*1024; A3 kc @ (40+kc)*1024; smalls f32 @ 45056:
// [0..15]=PS [16..19]=PB [20..23]=0.1*b3 [24..151]=b2

__device__ __forceinline__ h16x2 pkrtz(float a, float b){
  auto t = __builtin_amdgcn_cvt_pkrtz(a, b);
  h16x2 r; __builtin_memcpy(&r, &t, 4); return r;
}
__device__ __forceinline__ unsigned pkh(float a, float b){
  auto t = __builtin_amdgcn_cvt_pkrtz(a, b);
  unsigned r; __builtin_memcpy(&r, &t, 4); return r;
}

// packed GELU: y = x * (0.5 + xc*D(xc^2)), xc = clamp(x,±3.75)/4, deg-9 odd.
__device__ __forceinline__ h16x2 gelu_pk(h16x2 x){
  const h16x2 Q   = {(_Float16)0.25f,      (_Float16)0.25f};
  const h16x2 CLO = {(_Float16)-0.9375f,   (_Float16)-0.9375f};
  const h16x2 CHI = {(_Float16)0.9375f,    (_Float16)0.9375f};
  const h16x2 D4  = {(_Float16)2.639031f,  (_Float16)2.639031f};
  const h16x2 D3  = {(_Float16)-6.920503f, (_Float16)-6.920503f};
  const h16x2 D2  = {(_Float16)7.180759f,  (_Float16)7.180759f};
  const h16x2 D1  = {(_Float16)-3.960064f, (_Float16)-3.960064f};
  const h16x2 D0  = {(_Float16)1.590628f,  (_Float16)1.590628f};
  const h16x2 H   = {(_Float16)0.5f,       (_Float16)0.5f};
  h16x2 xs = x * Q;
  xs = __builtin_elementwise_max(xs, CLO);
  xs = __builtin_elementwise_min(xs, CHI);
  h16x2 t = xs * xs;
  h16x2 s = t*D4 + D3;
  s = s*t + D2;
  s = s*t + D1;
  s = s*t + D0;
  h16x2 phi = xs*s + H;
  return x * phi;
}

__device__ __forceinline__ void gelu4(const f32x4 c, unsigned& w0, unsigned& w1){
  h16x2 p0 = gelu_pk(pkrtz(c[0], c[1]));
  h16x2 p1 = gelu_pk(pkrtz(c[2], c[3]));
  __builtin_memcpy(&w0, &p0, 4);
  __builtin_memcpy(&w1, &p1, 4);
}

// ---------------- prepack (verbatim — validated) ----------------
__global__ void prepack(const float* __restrict__ W1, const float* __restrict__ b1,
                        const float* __restrict__ W2, const float* __restrict__ b2,
                        const float* __restrict__ W3, const float* __restrict__ b3,
                        const float* __restrict__ gg, const float* __restrict__ off,
                        const float* __restrict__ Pm, unsigned char* __restrict__ ws)
{
  int t = blockIdx.x * 256 + threadIdx.x;
  if (t >= 8 * 45 * 64) return;
  int l    = t / (45 * 64);
  int rem  = t % (45 * 64);
  int f    = rem / 64;
  int lane = rem % 64;
  int p = lane & 15, g = lane >> 4;
  unsigned char* lb = ws + l * LBYTES;

  if (f < 32) {
    int mf = f >> 2, kc = f & 3;
    const float* rw = W2 + l*16384 + (16*mf + p)*128 + 32*kc + 8*g;
    f32x4 u0 = *(const f32x4*)rw;
    f32x4 u1 = *(const f32x4*)(rw + 4);
    i32x4 w;
    w[0] = (int)pkh(u0[0], u0[1]); w[1] = (int)pkh(u0[2], u0[3]);
    w[2] = (int)pkh(u1[0], u1[1]); w[3] = (int)pkh(u1[2], u1[3]);
    *(i32x4*)(lb + f*1024 + lane*16) = w;
  } else if (f < 40) {
    int mf = f - 32;
    i32x4 w = (i32x4){0,0,0,0};
    if (g == 0) {
      int row = 16*mf + p;
      w[0] = (int)pkh(W1[l*256 + row*2 + 0], W1[l*256 + row*2 + 1]);
      w[1] = (int)pkh(b1[l*128 + row], 0.f);
    }
    *(i32x4*)(lb + f*1024 + lane*16) = w;
  } else if (f < 44) {
    int kc = f - 40;
    i32x4 w = (i32x4){0,0,0,0};
    if (p < 4) {
      const float* rw = W3 + l*512 + p*128 + 8*g + 32*kc;
      f32x4 u0 = *(const f32x4*)(rw);
      f32x4 u1 = *(const f32x4*)(rw + 4);
      w[0] = (int)pkh(0.1f*u0[0], 0.1f*u0[1]); w[1] = (int)pkh(0.1f*u0[2], 0.1f*u0[3]);
      w[2] = (int)pkh(0.1f*u1[0], 0.1f*u1[1]); w[3] = (int)pkh(0.1f*u1[2], 0.1f*u1[3]);
    }
    *(i32x4*)(lb + f*1024 + lane*16) = w;
  } else {
    float* sm = (float*)(lb + 45056);
    if (lane < 16) {
      int j = lane & 3;
      float scl = 0.2f * log1pf(expf(0.5f * gg[l*4 + j]));
      sm[lane] = Pm[l*16 + lane] * scl;
    } else if (lane < 20) {
      int i = lane - 16; float acc = 0.f;
      #pragma unroll
      for (int j = 0; j < 4; ++j) acc += Pm[l*16 + i*4 + j] * off[l*4 + j];
      sm[16 + i] = acc;
    } else if (lane < 24) {
      sm[lane] = 0.1f * b3[l*4 + (lane - 20)];
    }
    sm[24 + lane]      = b2[l*128 + lane];
    sm[24 + 64 + lane] = b2[l*128 + 64 + lane];
  }
}

// ---------------- main kernel ----------------
__global__ __launch_bounds__(256, 3) void inn_main(
    const float* __restrict__ XYZ,
    const unsigned char* __restrict__ ws,
    float* __restrict__ outp)
{
  // per wave: h buffer 4352B + xs state 1024B = 5376B; 4 waves = 21504B
  __shared__ __align__(16) unsigned char lds[4*5376];

  const int tid  = threadIdx.x;
  const int wid  = tid >> 6;
  const int lane = tid & 63;
  const int p    = lane & 15;
  const int g    = lane >> 4;
  unsigned char* hb = lds + wid*5376;
  float* xs = (float*)(hb + 4352);
  const long base_pt = (long)blockIdx.x*256 + wid*64;
  const f32x4 z4 = {0.f,0.f,0.f,0.f};
  const h16x8 zh = {(_Float16)0,(_Float16)0,(_Float16)0,(_Float16)0,
                    (_Float16)0,(_Float16)0,(_Float16)0,(_Float16)0};
  const unsigned loff = (unsigned)lane * 16u;

  if (lane < 16) {
    for (int s = 0; s < 4; ++s) {
      long pt = base_pt + s*16 + p;
      f32x4 v;
      v[0]=XYZ[pt*3+0]; v[1]=XYZ[pt*3+1]; v[2]=XYZ[pt*3+2]; v[3]=0.f;
      *(f32x4*)&xs[(s*16+p)*4] = v;
    }
  }
  MEMBAR();   // once, after state init

  for (int l = 0; l < 8; ++l) {
    const unsigned char* lb = ws + l * LBYTES;
    const float* sm = (const float*)(lb + 45056);
    f32x4 b3v = z4;
    if (g == 0) b3v = *(const f32x4*)(sm + 20);

    // ---- one 4-slot group per wave (64 points) ----
    h16x8 bx[4];
    #pragma unroll
    for (int t = 0; t < 4; ++t) {
      f32x4 xv = *(const f32x4*)&xs[(t*16+p)*4];
      h16x8 b = zh;
      if (g == 0) { b[0]=(_Float16)xv[0]; b[1]=(_Float16)xv[1]; b[2]=(_Float16)1.0f; }
      bx[t] = b;
    }
    h16x8 bfr1[4][4];   // [kc(=mfp)][slot]
    #pragma unroll
    for (int mfp = 0; mfp < 4; ++mfp) {
      h16x8 a1a = *(const h16x8*)(lb + (32 + 2*mfp)*1024 + loff);
      h16x8 a1b = *(const h16x8*)(lb + (33 + 2*mfp)*1024 + loff);
      f32x4 c1a[4], c1b[4];
      #pragma unroll
      for (int t = 0; t < 4; ++t) {
        c1a[t] = MFMA(a1a, bx[t], z4);
        c1b[t] = MFMA(a1b, bx[t], z4);
      }
      #pragma unroll
      for (int t = 0; t < 4; ++t) {
        i32x4 w; unsigned w0,w1,w2,w3;
        gelu4(c1a[t], w0, w1); gelu4(c1b[t], w2, w3);
        w[0]=(int)w0; w[1]=(int)w1; w[2]=(int)w2; w[3]=(int)w3;
        *(i32x4*)(hb + p*272 + (4*t + g)*16) = w;
      }
      #pragma unroll
      for (int t = 0; t < 4; ++t) {
        const unsigned char* ra = hb + p*272 + (4*t + 2*(g & 1))*16 + (g >> 1)*8;
        s16x4 lo = *(const s16x4*)(ra);
        s16x4 hi = *(const s16x4*)(ra + 16);
        h16x8 b;
        __builtin_memcpy(&b, &lo, 8);
        __builtin_memcpy(((char*)&b)+8, &hi, 8);
        bfr1[mfp][t] = b;
      }
    }

    // ---- G2+G3 fused per mf-pair ----
    f32x4 c3[4];
    #pragma unroll
    for (int t = 0; t < 4; ++t) c3[t] = b3v;
    #pragma unroll
    for (int mfp = 0; mfp < 4; ++mfp) {
      f32x4 bv0 = *(const f32x4*)(sm + 24 + 16*(2*mfp)   + 4*g);
      f32x4 bv1 = *(const f32x4*)(sm + 24 + 16*(2*mfp+1) + 4*g);
      f32x4 c2a[4], c2b[4];
      #pragma unroll
      for (int t = 0; t < 4; ++t) { c2a[t] = bv0; c2b[t] = bv1; }
      #pragma unroll
      for (int kc = 0; kc < 4; ++kc) {
        h16x8 af0 = *(const h16x8*)(lb + ((2*mfp)*4   + kc)*1024 + loff);
        h16x8 af1 = *(const h16x8*)(lb + ((2*mfp+1)*4 + kc)*1024 + loff);
        #pragma unroll
        for (int t = 0; t < 4; ++t) {
          c2a[t] = MFMA(af0, bfr1[kc][t], c2a[t]);
          c2b[t] = MFMA(af1, bfr1[kc][t], c2b[t]);
        }
      }
      h16x8 a3 = *(const h16x8*)(lb + (40 + mfp)*1024 + loff);
      #pragma unroll
      for (int t = 0; t < 4; ++t) {
        i32x4 w; unsigned w0,w1,w2,w3;
        gelu4(c2a[t], w0, w1); gelu4(c2b[t], w2, w3);
        w[0]=(int)w0; w[1]=(int)w1; w[2]=(int)w2; w[3]=(int)w3;
        *(i32x4*)(hb + p*272 + (4*t + g)*16) = w;
      }
      #pragma unroll
      for (int t = 0; t < 4; ++t) {
        const unsigned char* ra = hb + p*272 + (4*t + 2*(g & 1))*16 + (g >> 1)*8;
        s16x4 lo = *(const s16x4*)(ra);
        s16x4 hi = *(const s16x4*)(ra + 16);
        h16x8 b;
        __builtin_memcpy(&b, &lo, 8);
        __builtin_memcpy(((char*)&b)+8, &hi, 8);
        c3[t] = MFMA(a3, b, c3[t]);
      }
    }

    // ---- tails ----
    f32x4 ps0 = *(const f32x4*)(sm + 0);
    f32x4 ps1 = *(const f32x4*)(sm + 4);
    f32x4 ps2 = *(const f32x4*)(sm + 8);
    f32x4 ps3 = *(const f32x4*)(sm + 12);
    f32x4 pb  = *(const f32x4*)(sm + 16);
    int addr = p << 2;
    #pragma unroll
    for (int t = 0; t < 4; ++t) {
      f32x4 xv = *(const f32x4*)&xs[(t*16+p)*4];
      float a0 = __int_as_float(__builtin_amdgcn_ds_bpermute(addr, __float_as_int(c3[t][0])));
      float a1 = __int_as_float(__builtin_amdgcn_ds_bpermute(addr, __float_as_int(c3[t][1])));
      float a2 = __int_as_float(__builtin_amdgcn_ds_bpermute(addr, __float_as_int(c3[t][2])));
      float a3f= __int_as_float(__builtin_amdgcn_ds_bpermute(addr, __float_as_int(c3[t][3])));
      float t0 = __builtin_amdgcn_rcpf(1.f + __builtin_amdgcn_exp2f(2.8853901f * a0));
      float t1 = __builtin_amdgcn_rcpf(1.f + __builtin_amdgcn_exp2f(2.8853901f * a1));
      float e0 = __builtin_amdgcn_exp2f(__builtin_fmaf(-5.7707802f, t0, 2.8853901f));
      float e1 = __builtin_amdgcn_exp2f(__builtin_fmaf(-5.7707802f, t1, 2.8853901f));
      float v2 = __builtin_fmaf(xv[2], e0, a2);
      float v3 = __builtin_fmaf(xv[3], e1, a3f);
      f32x4 y;
      y[0] = __builtin_fmaf(ps0[0], xv[0], __builtin_fmaf(ps0[1], xv[1],
             __builtin_fmaf(ps0[2], v2, __builtin_fmaf(ps0[3], v3, pb[0]))));
      y[1] = __builtin_fmaf(ps1[0], xv[0], __builtin_fmaf(ps1[1], xv[1],
             __builtin_fmaf(ps1[2], v2, __builtin_fmaf(ps1[3], v3, pb[1]))));
      y[2] = __builtin_fmaf(ps2[0], xv[0], __builtin_fmaf(ps2[1], xv[1],
             __builtin_fmaf(ps2[2], v2, __builtin_fmaf(ps2[3], v3, pb[2]))));
      y[3] = __builtin_fmaf(ps3[0], xv[0], __builtin_fmaf(ps3[1], xv[1],
             __builtin_fmaf(ps3[2], v2, __builtin_fmaf(ps3[3], v3, pb[3]))));
      if (g == 0) *(f32x4*)&xs[(t*16+p)*4] = y;
    }
  }

  if (lane < 16) {
    for (int s = 0; s < 4; ++s) {
      long pt = base_pt + s*16 + p;
      f32x4 xv = *(const f32x4*)&xs[(s*16+p)*4];
      outp[pt*3+0] = xv[0];
      outp[pt*3+1] = xv[1];
      outp[pt*3+2] = xv[2];
    }
  }
}

extern "C" void kernel_launch(void* const* d_in, const int* in_sizes, int n_in,
                              void* d_out, int out_size, void* d_ws, size_t ws_size,
                              hipStream_t stream)
{
  const float* XYZ = (const float*)d_in[0];
  const float* W1  = (const float*)d_in[1];
  const float* b1  = (const float*)d_in[2];
  const float* W2  = (const float*)d_in[3];
  const float* b2  = (const float*)d_in[4];
  const float* W3  = (const float*)d_in[5];
  const float* b3  = (const float*)d_in[6];
  const float* g   = (const float*)d_in[7];
  const float* off = (const float*)d_in[8];
  const float* P   = (const float*)d_in[9];
  unsigned char* ws = (unsigned char*)d_ws;

  prepack<<<90, 256, 0, stream>>>(W1, b1, W2, b2, W3, b3, g, off, P, ws);

  int Bn = in_sizes[0] / 3;          // 524288
  int nblocks = Bn / 256;            // 2048 exact
  inn_main<<<nblocks, 256, 0, stream>>>(XYZ, ws, (float*)d_out);
}

// Round 21
// 330.235 us; speedup vs baseline: 1.0597x; 1.0021x over previous
//
#include <hip/hip_runtime.h>
#include <hip/hip_bf16.h>

// ColorINN R21: single-variable — h-buffer stride 272 -> 304 bytes.
// 272B = 68 dw ≡ 4 (mod 32) => write bank = 4(p+g+4t) mod 32 => ~8-way LDS
// bank conflict on every h write/read (SQ_LDS_BANK_CONFLICT saturated at
// 2^23/2^24 all session). 304B = 76 dw ≡ 12 (mod 32): banks 12p+4g+16t and
// 12p+8(g&1)+2(g>>1)+16t are each 32-distinct over (p mod 8, g) => exactly
// 2 lanes/bank = free (m136). Body otherwise verbatim R20 (R18 structure).

#define MEMBAR() asm volatile("" ::: "memory")

typedef float    f32x4 __attribute__((ext_vector_type(4)));
typedef short    s16x4 __attribute__((ext_vector_type(4), may_alias));
typedef int      i32x4 __attribute__((ext_vector_type(4), may_alias));
typedef _Float16 h16x2 __attribute__((ext_vector_type(2)));
typedef _Float16 h16x8 __attribute__((ext_vector_type(8)));

#define MFMA(a,b,c) __builtin_amdgcn_mfma_f32_16x16x32_f16((a),(b),(c),0,0,0)

#define LBYTES 46080
#define HSTRIDE 304
// per-layer ws layout (validated R14/R15): A2 frag f=mf*4+kc @ f*1024 (32KB);
// A1 mf @ (32+mf)*1024; A3 kc @ (40+kc)*1024; smalls f32 @ 45056:
// [0..15]=PS [16..19]=PB [20..23]=0.1*b3 [24..151]=b2

__device__ __forceinline__ h16x2 pkrtz(float a, float b){
  auto t = __builtin_amdgcn_cvt_pkrtz(a, b);
  h16x2 r; __builtin_memcpy(&r, &t, 4); return r;
}
__device__ __forceinline__ unsigned pkh(float a, float b){
  auto t = __builtin_amdgcn_cvt_pkrtz(a, b);
  unsigned r; __builtin_memcpy(&r, &t, 4); return r;
}

// packed GELU: y = x * (0.5 + xc*D(xc^2)), xc = clamp(x,±3.75)/4, deg-9 odd.
__device__ __forceinline__ h16x2 gelu_pk(h16x2 x){
  const h16x2 Q   = {(_Float16)0.25f,      (_Float16)0.25f};
  const h16x2 CLO = {(_Float16)-0.9375f,   (_Float16)-0.9375f};
  const h16x2 CHI = {(_Float16)0.9375f,    (_Float16)0.9375f};
  const h16x2 D4  = {(_Float16)2.639031f,  (_Float16)2.639031f};
  const h16x2 D3  = {(_Float16)-6.920503f, (_Float16)-6.920503f};
  const h16x2 D2  = {(_Float16)7.180759f,  (_Float16)7.180759f};
  const h16x2 D1  = {(_Float16)-3.960064f, (_Float16)-3.960064f};
  const h16x2 D0  = {(_Float16)1.590628f,  (_Float16)1.590628f};
  const h16x2 H   = {(_Float16)0.5f,       (_Float16)0.5f};
  h16x2 xs = x * Q;
  xs = __builtin_elementwise_max(xs, CLO);
  xs = __builtin_elementwise_min(xs, CHI);
  h16x2 t = xs * xs;
  h16x2 s = t*D4 + D3;
  s = s*t + D2;
  s = s*t + D1;
  s = s*t + D0;
  h16x2 phi = xs*s + H;
  return x * phi;
}

__device__ __forceinline__ void gelu4(const f32x4 c, unsigned& w0, unsigned& w1){
  h16x2 p0 = gelu_pk(pkrtz(c[0], c[1]));
  h16x2 p1 = gelu_pk(pkrtz(c[2], c[3]));
  __builtin_memcpy(&w0, &p0, 4);
  __builtin_memcpy(&w1, &p1, 4);
}

// ---------------- prepack (verbatim — validated) ----------------
__global__ void prepack(const float* __restrict__ W1, const float* __restrict__ b1,
                        const float* __restrict__ W2, const float* __restrict__ b2,
                        const float* __restrict__ W3, const float* __restrict__ b3,
                        const float* __restrict__ gg, const float* __restrict__ off,
                        const float* __restrict__ Pm, unsigned char* __restrict__ ws)
{
  int t = blockIdx.x * 256 + threadIdx.x;
  if (t >= 8 * 45 * 64) return;
  int l    = t / (45 * 64);
  int rem  = t % (45 * 64);
  int f    = rem / 64;
  int lane = rem % 64;
  int p = lane & 15, g = lane >> 4;
  unsigned char* lb = ws + l * LBYTES;

  if (f < 32) {
    int mf = f >> 2, kc = f & 3;
    const float* rw = W2 + l*16384 + (16*mf + p)*128 + 32*kc + 8*g;
    f32x4 u0 = *(const f32x4*)rw;
    f32x4 u1 = *(const f32x4*)(rw + 4);
    i32x4 w;
    w[0] = (int)pkh(u0[0], u0[1]); w[1] = (int)pkh(u0[2], u0[3]);
    w[2] = (int)pkh(u1[0], u1[1]); w[3] = (int)pkh(u1[2], u1[3]);
    *(i32x4*)(lb + f*1024 + lane*16) = w;
  } else if (f < 40) {
    int mf = f - 32;
    i32x4 w = (i32x4){0,0,0,0};
    if (g == 0) {
      int row = 16*mf + p;
      w[0] = (int)pkh(W1[l*256 + row*2 + 0], W1[l*256 + row*2 + 1]);
      w[1] = (int)pkh(b1[l*128 + row], 0.f);
    }
    *(i32x4*)(lb + f*1024 + lane*16) = w;
  } else if (f < 44) {
    int kc = f - 40;
    i32x4 w = (i32x4){0,0,0,0};
    if (p < 4) {
      const float* rw = W3 + l*512 + p*128 + 8*g + 32*kc;
      f32x4 u0 = *(const f32x4*)(rw);
      f32x4 u1 = *(const f32x4*)(rw + 4);
      w[0] = (int)pkh(0.1f*u0[0], 0.1f*u0[1]); w[1] = (int)pkh(0.1f*u0[2], 0.1f*u0[3]);
      w[2] = (int)pkh(0.1f*u1[0], 0.1f*u1[1]); w[3] = (int)pkh(0.1f*u1[2], 0.1f*u1[3]);
    }
    *(i32x4*)(lb + f*1024 + lane*16) = w;
  } else {
    float* sm = (float*)(lb + 45056);
    if (lane < 16) {
      int j = lane & 3;
      float scl = 0.2f * log1pf(expf(0.5f * gg[l*4 + j]));
      sm[lane] = Pm[l*16 + lane] * scl;
    } else if (lane < 20) {
      int i = lane - 16; float acc = 0.f;
      #pragma unroll
      for (int j = 0; j < 4; ++j) acc += Pm[l*16 + i*4 + j] * off[l*4 + j];
      sm[16 + i] = acc;
    } else if (lane < 24) {
      sm[lane] = 0.1f * b3[l*4 + (lane - 20)];
    }
    sm[24 + lane]      = b2[l*128 + lane];
    sm[24 + 64 + lane] = b2[l*128 + 64 + lane];
  }
}

// ---------------- main kernel ----------------
__global__ __launch_bounds__(256, 3) void inn_main(
    const float* __restrict__ XYZ,
    const unsigned char* __restrict__ ws,
    float* __restrict__ outp)
{
  // per wave: h buffer 16*304=4864B + xs state 1024B = 5888B; 4 waves = 23552B
  __shared__ __align__(16) unsigned char lds[4*5888];

  const int tid  = threadIdx.x;
  const int wid  = tid >> 6;
  const int lane = tid & 63;
  const int p    = lane & 15;
  const int g    = lane >> 4;
  unsigned char* hb = lds + wid*5888;
  float* xs = (float*)(hb + 4864);
  const long base_pt = (long)blockIdx.x*256 + wid*64;
  const f32x4 z4 = {0.f,0.f,0.f,0.f};
  const h16x8 zh = {(_Float16)0,(_Float16)0,(_Float16)0,(_Float16)0,
                    (_Float16)0,(_Float16)0,(_Float16)0,(_Float16)0};
  const unsigned loff = (unsigned)lane * 16u;

  if (lane < 16) {
    for (int s = 0; s < 4; ++s) {
      long pt = base_pt + s*16 + p;
      f32x4 v;
      v[0]=XYZ[pt*3+0]; v[1]=XYZ[pt*3+1]; v[2]=XYZ[pt*3+2]; v[3]=0.f;
      *(f32x4*)&xs[(s*16+p)*4] = v;
    }
  }
  MEMBAR();   // once, after state init

  for (int l = 0; l < 8; ++l) {
    const unsigned char* lb = ws + l * LBYTES;
    const float* sm = (const float*)(lb + 45056);
    f32x4 b3v = z4;
    if (g == 0) b3v = *(const f32x4*)(sm + 20);

    // ---- one 4-slot group per wave (64 points) ----
    h16x8 bx[4];
    #pragma unroll
    for (int t = 0; t < 4; ++t) {
      f32x4 xv = *(const f32x4*)&xs[(t*16+p)*4];
      h16x8 b = zh;
      if (g == 0) { b[0]=(_Float16)xv[0]; b[1]=(_Float16)xv[1]; b[2]=(_Float16)1.0f; }
      bx[t] = b;
    }
    h16x8 bfr1[4][4];   // [kc(=mfp)][slot]
    #pragma unroll
    for (int mfp = 0; mfp < 4; ++mfp) {
      h16x8 a1a = *(const h16x8*)(lb + (32 + 2*mfp)*1024 + loff);
      h16x8 a1b = *(const h16x8*)(lb + (33 + 2*mfp)*1024 + loff);
      f32x4 c1a[4], c1b[4];
      #pragma unroll
      for (int t = 0; t < 4; ++t) {
        c1a[t] = MFMA(a1a, bx[t], z4);
        c1b[t] = MFMA(a1b, bx[t], z4);
      }
      #pragma unroll
      for (int t = 0; t < 4; ++t) {
        i32x4 w; unsigned w0,w1,w2,w3;
        gelu4(c1a[t], w0, w1); gelu4(c1b[t], w2, w3);
        w[0]=(int)w0; w[1]=(int)w1; w[2]=(int)w2; w[3]=(int)w3;
        *(i32x4*)(hb + p*HSTRIDE + (4*t + g)*16) = w;
      }
      #pragma unroll
      for (int t = 0; t < 4; ++t) {
        const unsigned char* ra = hb + p*HSTRIDE + (4*t + 2*(g & 1))*16 + (g >> 1)*8;
        s16x4 lo = *(const s16x4*)(ra);
        s16x4 hi = *(const s16x4*)(ra + 16);
        h16x8 b;
        __builtin_memcpy(&b, &lo, 8);
        __builtin_memcpy(((char*)&b)+8, &hi, 8);
        bfr1[mfp][t] = b;
      }
    }

    // ---- G2+G3 fused per mf-pair ----
    f32x4 c3[4];
    #pragma unroll
    for (int t = 0; t < 4; ++t) c3[t] = b3v;
    #pragma unroll
    for (int mfp = 0; mfp < 4; ++mfp) {
      f32x4 bv0 = *(const f32x4*)(sm + 24 + 16*(2*mfp)   + 4*g);
      f32x4 bv1 = *(const f32x4*)(sm + 24 + 16*(2*mfp+1) + 4*g);
      f32x4 c2a[4], c2b[4];
      #pragma unroll
      for (int t = 0; t < 4; ++t) { c2a[t] = bv0; c2b[t] = bv1; }
      #pragma unroll
      for (int kc = 0; kc < 4; ++kc) {
        h16x8 af0 = *(const h16x8*)(lb + ((2*mfp)*4   + kc)*1024 + loff);
        h16x8 af1 = *(const h16x8*)(lb + ((2*mfp+1)*4 + kc)*1024 + loff);
        #pragma unroll
        for (int t = 0; t < 4; ++t) {
          c2a[t] = MFMA(af0, bfr1[kc][t], c2a[t]);
          c2b[t] = MFMA(af1, bfr1[kc][t], c2b[t]);
        }
      }
      h16x8 a3 = *(const h16x8*)(lb + (40 + mfp)*1024 + loff);
      #pragma unroll
      for (int t = 0; t < 4; ++t) {
        i32x4 w; unsigned w0,w1,w2,w3;
        gelu4(c2a[t], w0, w1); gelu4(c2b[t], w2, w3);
        w[0]=(int)w0; w[1]=(int)w1; w[2]=(int)w2; w[3]=(int)w3;
        *(i32x4*)(hb + p*HSTRIDE + (4*t + g)*16) = w;
      }
      #pragma unroll
      for (int t = 0; t < 4; ++t) {
        const unsigned char* ra = hb + p*HSTRIDE + (4*t + 2*(g & 1))*16 + (g >> 1)*8;
        s16x4 lo = *(const s16x4*)(ra);
        s16x4 hi = *(const s16x4*)(ra + 16);
        h16x8 b;
        __builtin_memcpy(&b, &lo, 8);
        __builtin_memcpy(((char*)&b)+8, &hi, 8);
        c3[t] = MFMA(a3, b, c3[t]);
      }
    }

    // ---- tails ----
    f32x4 ps0 = *(const f32x4*)(sm + 0);
    f32x4 ps1 = *(const f32x4*)(sm + 4);
    f32x4 ps2 = *(const f32x4*)(sm + 8);
    f32x4 ps3 = *(const f32x4*)(sm + 12);
    f32x4 pb  = *(const f32x4*)(sm + 16);
    int addr = p << 2;
    #pragma unroll
    for (int t = 0; t < 4; ++t) {
      f32x4 xv = *(const f32x4*)&xs[(t*16+p)*4];
      float a0 = __int_as_float(__builtin_amdgcn_ds_bpermute(addr, __float_as_int(c3[t][0])));
      float a1 = __int_as_float(__builtin_amdgcn_ds_bpermute(addr, __float_as_int(c3[t][1])));
      float a2 = __int_as_float(__builtin_amdgcn_ds_bpermute(addr, __float_as_int(c3[t][2])));
      float a3f= __int_as_float(__builtin_amdgcn_ds_bpermute(addr, __float_as_int(c3[t][3])));
      float t0 = __builtin_amdgcn_rcpf(1.f + __builtin_amdgcn_exp2f(2.8853901f * a0));
      float t1 = __builtin_amdgcn_rcpf(1.f + __builtin_amdgcn_exp2f(2.8853901f * a1));
      float e0 = __builtin_amdgcn_exp2f(__builtin_fmaf(-5.7707802f, t0, 2.8853901f));
      float e1 = __builtin_amdgcn_exp2f(__builtin_fmaf(-5.7707802f, t1, 2.8853901f));
      float v2 = __builtin_fmaf(xv[2], e0, a2);
      float v3 = __builtin_fmaf(xv[3], e1, a3f);
      f32x4 y;
      y[0] = __builtin_fmaf(ps0[0], xv[0], __builtin_fmaf(ps0[1], xv[1],
             __builtin_fmaf(ps0[2], v2, __builtin_fmaf(ps0[3], v3, pb[0]))));
      y[1] = __builtin_fmaf(ps1[0], xv[0], __builtin_fmaf(ps1[1], xv[1],
             __builtin_fmaf(ps1[2], v2, __builtin_fmaf(ps1[3], v3, pb[1]))));
      y[2] = __builtin_fmaf(ps2[0], xv[0], __builtin_fmaf(ps2[1], xv[1],
             __builtin_fmaf(ps2[2], v2, __builtin_fmaf(ps2[3], v3, pb[2]))));
      y[3] = __builtin_fmaf(ps3[0], xv[0], __builtin_fmaf(ps3[1], xv[1],
             __builtin_fmaf(ps3[2], v2, __builtin_fmaf(ps3[3], v3, pb[3]))));
      if (g == 0) *(f32x4*)&xs[(t*16+p)*4] = y;
    }
  }

  if (lane < 16) {
    for (int s = 0; s < 4; ++s) {
      long pt = base_pt + s*16 + p;
      f32x4 xv = *(const f32x4*)&xs[(s*16+p)*4];
      outp[pt*3+0] = xv[0];
      outp[pt*3+1] = xv[1];
      outp[pt*3+2] = xv[2];
    }
  }
}

extern "C" void kernel_launch(void* const* d_in, const int* in_sizes, int n_in,
                              void* d_out, int out_size, void* d_ws, size_t ws_size,
                              hipStream_t stream)
{
  const float* XYZ = (const float*)d_in[0];
  const float* W1  = (const float*)d_in[1];
  const float* b1  = (const float*)d_in[2];
  const float* W2  = (const float*)d_in[3];
  const float* b2  = (const float*)d_in[4];
  const float* W3  = (const float*)d_in[5];
  const float* b3  = (const float*)d_in[6];
  const float* g   = (const float*)d_in[7];
  const float* off = (const float*)d_in[8];
  const float* P   = (const float*)d_in[9];
  unsigned char* ws = (unsigned char*)d_ws;

  prepack<<<90, 256, 0, stream>>>(W1, b1, W2, b2, W3, b3, g, off, P, ws);

  int Bn = in_sizes[0] / 3;          // 524288
  int nblocks = Bn / 256;            // 2048 exact
  inn_main<<<nblocks, 256, 0, stream>>>(XYZ, ws, (float*)d_out);
}

// Round 22
// 313.122 us; speedup vs baseline: 1.1176x; 1.0547x over previous
//
#include <hip/hip_runtime.h>
#include <hip/hip_bf16.h>

// ColorINN R22: G1 computed DIRECTLY in registers (no MFMA, no LDS relayout).
// G1 is a 2->128 matmul: bfr1[kc][t][j] = gelu(w1[n,0]x0 + w1[n,1]x1 + b1[n]),
// n = 32kc+8g+j (mapping == the session-validated B-frag layout). Packed-f16
// fma, 48 ops per (kc,t), replaces 32 MFMA + 48 LDS ops + serial relayout
// chain per layer-wave. W1 prepacked per (kc,g) as 3x h16x8. Rest = R21.

#define MEMBAR() asm volatile("" ::: "memory")

typedef float    f32x4 __attribute__((ext_vector_type(4)));
typedef short    s16x4 __attribute__((ext_vector_type(4), may_alias));
typedef int      i32x4 __attribute__((ext_vector_type(4), may_alias));
typedef _Float16 h16x2 __attribute__((ext_vector_type(2)));
typedef _Float16 h16x8 __attribute__((ext_vector_type(8)));

#define MFMA(a,b,c) __builtin_amdgcn_mfma_f32_16x16x32_f16((a),(b),(c),0,0,0)

#define LBYTES 46080
#define HSTRIDE 304
// per-layer ws layout: A2 frag f=mf*4+kc @ f*1024 (32KB); W1-direct @ 32768:
// per (kc,g) combo c=kc*4+g, 48B = {w1col0 h16x8, w1col1 h16x8, b1 h16x8},
// n = 32kc+8g+j; A3 kc @ (40+kc)*1024; smalls f32 @ 45056:
// [0..15]=PS [16..19]=PB [20..23]=0.1*b3 [24..151]=b2

__device__ __forceinline__ h16x2 pkrtz(float a, float b){
  auto t = __builtin_amdgcn_cvt_pkrtz(a, b);
  h16x2 r; __builtin_memcpy(&r, &t, 4); return r;
}
__device__ __forceinline__ unsigned pkh(float a, float b){
  auto t = __builtin_amdgcn_cvt_pkrtz(a, b);
  unsigned r; __builtin_memcpy(&r, &t, 4); return r;
}

// packed GELU: y = x * (0.5 + xc*D(xc^2)), xc = clamp(x,±3.75)/4, deg-9 odd.
__device__ __forceinline__ h16x2 gelu_pk(h16x2 x){
  const h16x2 Q   = {(_Float16)0.25f,      (_Float16)0.25f};
  const h16x2 CLO = {(_Float16)-0.9375f,   (_Float16)-0.9375f};
  const h16x2 CHI = {(_Float16)0.9375f,    (_Float16)0.9375f};
  const h16x2 D4  = {(_Float16)2.639031f,  (_Float16)2.639031f};
  const h16x2 D3  = {(_Float16)-6.920503f, (_Float16)-6.920503f};
  const h16x2 D2  = {(_Float16)7.180759f,  (_Float16)7.180759f};
  const h16x2 D1  = {(_Float16)-3.960064f, (_Float16)-3.960064f};
  const h16x2 D0  = {(_Float16)1.590628f,  (_Float16)1.590628f};
  const h16x2 H   = {(_Float16)0.5f,       (_Float16)0.5f};
  h16x2 xs = x * Q;
  xs = __builtin_elementwise_max(xs, CLO);
  xs = __builtin_elementwise_min(xs, CHI);
  h16x2 t = xs * xs;
  h16x2 s = t*D4 + D3;
  s = s*t + D2;
  s = s*t + D1;
  s = s*t + D0;
  h16x2 phi = xs*s + H;
  return x * phi;
}

__device__ __forceinline__ void gelu4(const f32x4 c, unsigned& w0, unsigned& w1){
  h16x2 p0 = gelu_pk(pkrtz(c[0], c[1]));
  h16x2 p1 = gelu_pk(pkrtz(c[2], c[3]));
  __builtin_memcpy(&w0, &p0, 4);
  __builtin_memcpy(&w1, &p1, 4);
}

// ---------------- prepack ----------------
__global__ void prepack(const float* __restrict__ W1, const float* __restrict__ b1,
                        const float* __restrict__ W2, const float* __restrict__ b2,
                        const float* __restrict__ W3, const float* __restrict__ b3,
                        const float* __restrict__ gg, const float* __restrict__ off,
                        const float* __restrict__ Pm, unsigned char* __restrict__ ws)
{
  int t = blockIdx.x * 256 + threadIdx.x;
  if (t >= 8 * 45 * 64) return;
  int l    = t / (45 * 64);
  int rem  = t % (45 * 64);
  int f    = rem / 64;
  int lane = rem % 64;
  int p = lane & 15, g = lane >> 4;
  unsigned char* lb = ws + l * LBYTES;

  if (f < 32) {          // A2 fragment (validated)
    int mf = f >> 2, kc = f & 3;
    const float* rw = W2 + l*16384 + (16*mf + p)*128 + 32*kc + 8*g;
    f32x4 u0 = *(const f32x4*)rw;
    f32x4 u1 = *(const f32x4*)(rw + 4);
    i32x4 w;
    w[0] = (int)pkh(u0[0], u0[1]); w[1] = (int)pkh(u0[2], u0[3]);
    w[2] = (int)pkh(u1[0], u1[1]); w[3] = (int)pkh(u1[2], u1[3]);
    *(i32x4*)(lb + f*1024 + lane*16) = w;
  } else if (f == 32) {  // W1-direct: combo c=lane (kc=c>>2, gq=c&3), 48B each
    if (lane < 16) {
      int kc = lane >> 2, gq = lane & 3;
      unsigned w0p[4], w1p[4], bbp[4];
      #pragma unroll
      for (int j2 = 0; j2 < 4; ++j2) {
        int n0 = 32*kc + 8*gq + 2*j2;
        int n1 = n0 + 1;
        w0p[j2] = pkh(W1[l*256 + n0*2 + 0], W1[l*256 + n1*2 + 0]);
        w1p[j2] = pkh(W1[l*256 + n0*2 + 1], W1[l*256 + n1*2 + 1]);
        bbp[j2] = pkh(b1[l*128 + n0],       b1[l*128 + n1]);
      }
      unsigned char* dst = lb + 32*1024 + lane*48;
      i32x4 a, b, c;
      #pragma unroll
      for (int q = 0; q < 4; ++q) { a[q]=(int)w0p[q]; b[q]=(int)w1p[q]; c[q]=(int)bbp[q]; }
      *(i32x4*)(dst)      = a;
      *(i32x4*)(dst + 16) = b;
      *(i32x4*)(dst + 32) = c;
    }
  } else if (f >= 40 && f < 44) {   // A3 (validated)
    int kc = f - 40;
    i32x4 w = (i32x4){0,0,0,0};
    if (p < 4) {
      const float* rw = W3 + l*512 + p*128 + 8*g + 32*kc;
      f32x4 u0 = *(const f32x4*)(rw);
      f32x4 u1 = *(const f32x4*)(rw + 4);
      w[0] = (int)pkh(0.1f*u0[0], 0.1f*u0[1]); w[1] = (int)pkh(0.1f*u0[2], 0.1f*u0[3]);
      w[2] = (int)pkh(0.1f*u1[0], 0.1f*u1[1]); w[3] = (int)pkh(0.1f*u1[2], 0.1f*u1[3]);
    }
    *(i32x4*)(lb + f*1024 + lane*16) = w;
  } else if (f == 44) {  // smalls (validated)
    float* sm = (float*)(lb + 45056);
    if (lane < 16) {
      int j = lane & 3;
      float scl = 0.2f * log1pf(expf(0.5f * gg[l*4 + j]));
      sm[lane] = Pm[l*16 + lane] * scl;
    } else if (lane < 20) {
      int i = lane - 16; float acc = 0.f;
      #pragma unroll
      for (int j = 0; j < 4; ++j) acc += Pm[l*16 + i*4 + j] * off[l*4 + j];
      sm[16 + i] = acc;
    } else if (lane < 24) {
      sm[lane] = 0.1f * b3[l*4 + (lane - 20)];
    }
    sm[24 + lane]      = b2[l*128 + lane];
    sm[24 + 64 + lane] = b2[l*128 + 64 + lane];
  }
}

// ---------------- main kernel ----------------
__global__ __launch_bounds__(256, 3) void inn_main(
    const float* __restrict__ XYZ,
    const unsigned char* __restrict__ ws,
    float* __restrict__ outp)
{
  // per wave: h buffer 16*304=4864B + xs state 1024B = 5888B; 4 waves = 23552B
  __shared__ __align__(16) unsigned char lds[4*5888];

  const int tid  = threadIdx.x;
  const int wid  = tid >> 6;
  const int lane = tid & 63;
  const int p    = lane & 15;
  const int g    = lane >> 4;
  unsigned char* hb = lds + wid*5888;
  float* xs = (float*)(hb + 4864);
  const long base_pt = (long)blockIdx.x*256 + wid*64;
  const f32x4 z4 = {0.f,0.f,0.f,0.f};
  const unsigned loff = (unsigned)lane * 16u;

  if (lane < 16) {
    for (int s = 0; s < 4; ++s) {
      long pt = base_pt + s*16 + p;
      f32x4 v;
      v[0]=XYZ[pt*3+0]; v[1]=XYZ[pt*3+1]; v[2]=XYZ[pt*3+2]; v[3]=0.f;
      *(f32x4*)&xs[(s*16+p)*4] = v;
    }
  }
  MEMBAR();   // once, after state init

  for (int l = 0; l < 8; ++l) {
    const unsigned char* lb = ws + l * LBYTES;
    const float* sm = (const float*)(lb + 45056);
    f32x4 b3v = z4;
    if (g == 0) b3v = *(const f32x4*)(sm + 20);

    // ---- G1 direct: bfr1[kc][t][j] = gelu(w0[n]x0 + w1[n]x1 + b[n]),
    //      n = 32kc+8g+j, point = base+t*16+p. Pure VALU, no MFMA/LDS. ----
    h16x2 X0[4], X1[4];
    #pragma unroll
    for (int t = 0; t < 4; ++t) {
      f32x4 xv = *(const f32x4*)&xs[(t*16+p)*4];
      X0[t] = pkrtz(xv[0], xv[0]);
      X1[t] = pkrtz(xv[1], xv[1]);
    }
    h16x8 bfr1[4][4];   // [kc][slot]
    #pragma unroll
    for (int kc = 0; kc < 4; ++kc) {
      const unsigned char* wd = lb + 32*1024 + (kc*4 + g)*48;
      h16x2 w0p[4], w1p[4], bbp[4];
      __builtin_memcpy(w0p, wd,      16);
      __builtin_memcpy(w1p, wd + 16, 16);
      __builtin_memcpy(bbp, wd + 32, 16);
      #pragma unroll
      for (int t = 0; t < 4; ++t) {
        h16x2 hp[4];
        #pragma unroll
        for (int j2 = 0; j2 < 4; ++j2) {
          h16x2 v = w0p[j2]*X0[t] + w1p[j2]*X1[t] + bbp[j2];
          hp[j2] = gelu_pk(v);
        }
        __builtin_memcpy(&bfr1[kc][t], hp, 16);
      }
    }

    // ---- G2+G3 fused per mf-pair (unchanged) ----
    f32x4 c3[4];
    #pragma unroll
    for (int t = 0; t < 4; ++t) c3[t] = b3v;
    #pragma unroll
    for (int mfp = 0; mfp < 4; ++mfp) {
      f32x4 bv0 = *(const f32x4*)(sm + 24 + 16*(2*mfp)   + 4*g);
      f32x4 bv1 = *(const f32x4*)(sm + 24 + 16*(2*mfp+1) + 4*g);
      f32x4 c2a[4], c2b[4];
      #pragma unroll
      for (int t = 0; t < 4; ++t) { c2a[t] = bv0; c2b[t] = bv1; }
      #pragma unroll
      for (int kc = 0; kc < 4; ++kc) {
        h16x8 af0 = *(const h16x8*)(lb + ((2*mfp)*4   + kc)*1024 + loff);
        h16x8 af1 = *(const h16x8*)(lb + ((2*mfp+1)*4 + kc)*1024 + loff);
        #pragma unroll
        for (int t = 0; t < 4; ++t) {
          c2a[t] = MFMA(af0, bfr1[kc][t], c2a[t]);
          c2b[t] = MFMA(af1, bfr1[kc][t], c2b[t]);
        }
      }
      h16x8 a3 = *(const h16x8*)(lb + (40 + mfp)*1024 + loff);
      #pragma unroll
      for (int t = 0; t < 4; ++t) {
        i32x4 w; unsigned w0,w1,w2,w3;
        gelu4(c2a[t], w0, w1); gelu4(c2b[t], w2, w3);
        w[0]=(int)w0; w[1]=(int)w1; w[2]=(int)w2; w[3]=(int)w3;
        *(i32x4*)(hb + p*HSTRIDE + (4*t + g)*16) = w;
      }
      #pragma unroll
      for (int t = 0; t < 4; ++t) {
        const unsigned char* ra = hb + p*HSTRIDE + (4*t + 2*(g & 1))*16 + (g >> 1)*8;
        s16x4 lo = *(const s16x4*)(ra);
        s16x4 hi = *(const s16x4*)(ra + 16);
        h16x8 b;
        __builtin_memcpy(&b, &lo, 8);
        __builtin_memcpy(((char*)&b)+8, &hi, 8);
        c3[t] = MFMA(a3, b, c3[t]);
      }
    }

    // ---- tails (unchanged) ----
    f32x4 ps0 = *(const f32x4*)(sm + 0);
    f32x4 ps1 = *(const f32x4*)(sm + 4);
    f32x4 ps2 = *(const f32x4*)(sm + 8);
    f32x4 ps3 = *(const f32x4*)(sm + 12);
    f32x4 pb  = *(const f32x4*)(sm + 16);
    int addr = p << 2;
    #pragma unroll
    for (int t = 0; t < 4; ++t) {
      f32x4 xv = *(const f32x4*)&xs[(t*16+p)*4];
      float a0 = __int_as_float(__builtin_amdgcn_ds_bpermute(addr, __float_as_int(c3[t][0])));
      float a1 = __int_as_float(__builtin_amdgcn_ds_bpermute(addr, __float_as_int(c3[t][1])));
      float a2 = __int_as_float(__builtin_amdgcn_ds_bpermute(addr, __float_as_int(c3[t][2])));
      float a3f= __int_as_float(__builtin_amdgcn_ds_bpermute(addr, __float_as_int(c3[t][3])));
      float t0 = __builtin_amdgcn_rcpf(1.f + __builtin_amdgcn_exp2f(2.8853901f * a0));
      float t1 = __builtin_amdgcn_rcpf(1.f + __builtin_amdgcn_exp2f(2.8853901f * a1));
      float e0 = __builtin_amdgcn_exp2f(__builtin_fmaf(-5.7707802f, t0, 2.8853901f));
      float e1 = __builtin_amdgcn_exp2f(__builtin_fmaf(-5.7707802f, t1, 2.8853901f));
      float v2 = __builtin_fmaf(xv[2], e0, a2);
      float v3 = __builtin_fmaf(xv[3], e1, a3f);
      f32x4 y;
      y[0] = __builtin_fmaf(ps0[0], xv[0], __builtin_fmaf(ps0[1], xv[1],
             __builtin_fmaf(ps0[2], v2, __builtin_fmaf(ps0[3], v3, pb[0]))));
      y[1] = __builtin_fmaf(ps1[0], xv[0], __builtin_fmaf(ps1[1], xv[1],
             __builtin_fmaf(ps1[2], v2, __builtin_fmaf(ps1[3], v3, pb[1]))));
      y[2] = __builtin_fmaf(ps2[0], xv[0], __builtin_fmaf(ps2[1], xv[1],
             __builtin_fmaf(ps2[2], v2, __builtin_fmaf(ps2[3], v3, pb[2]))));
      y[3] = __builtin_fmaf(ps3[0], xv[0], __builtin_fmaf(ps3[1], xv[1],
             __builtin_fmaf(ps3[2], v2, __builtin_fmaf(ps3[3], v3, pb[3]))));
      if (g == 0) *(f32x4*)&xs[(t*16+p)*4] = y;
    }
  }

  if (lane < 16) {
    for (int s = 0; s < 4; ++s) {
      long pt = base_pt + s*16 + p;
      f32x4 xv = *(const f32x4*)&xs[(s*16+p)*4];
      outp[pt*3+0] = xv[0];
      outp[pt*3+1] = xv[1];
      outp[pt*3+2] = xv[2];
    }
  }
}

extern "C" void kernel_launch(void* const* d_in, const int* in_sizes, int n_in,
                              void* d_out, int out_size, void* d_ws, size_t ws_size,
                              hipStream_t stream)
{
  const float* XYZ = (const float*)d_in[0];
  const float* W1  = (const float*)d_in[1];
  const float* b1  = (const float*)d_in[2];
  const float* W2  = (const float*)d_in[3];
  const float* b2  = (const float*)d_in[4];
  const float* W3  = (const float*)d_in[5];
  const float* b3  = (const float*)d_in[6];
  const float* g   = (const float*)d_in[7];
  const float* off = (const float*)d_in[8];
  const float* P   = (const float*)d_in[9];
  unsigned char* ws = (unsigned char*)d_ws;

  prepack<<<90, 256, 0, stream>>>(W1, b1, W2, b2, W3, b3, g, off, P, ws);

  int Bn = in_sizes[0] / 3;          // 524288
  int nblocks = Bn / 256;            // 2048 exact
  inn_main<<<nblocks, 256, 0, stream>>>(XYZ, ws, (float*)d_out);
}

// Round 23
// 295.322 us; speedup vs baseline: 1.1850x; 1.0603x over previous
//
#include <hip/hip_runtime.h>
#include <hip/hip_bf16.h>

// ColorINN R23: two VALU cuts on R22 (313us, VALU 71% + MFMA 22% = 93% issue).
// (1) Tail de-replication: 16 bpermutes gather a[t][i] on every lane; each
//     lane cndmask-selects slot t=g (static idx) and computes ONE tail
//     (was 4x replicated). 104 -> 38 VALU per wave-layer.
// (2) GELU 1/4-prescale folded into W2/b2/W1d at prepack: MFMA output = x/4,
//     gelu y = xin*(2 + xq*D'(xq^2)), D'=4D -> 10 -> 9 ops per gelu_pk.

#define MEMBAR() asm volatile("" ::: "memory")

typedef float    f32x4 __attribute__((ext_vector_type(4)));
typedef short    s16x4 __attribute__((ext_vector_type(4), may_alias));
typedef int      i32x4 __attribute__((ext_vector_type(4), may_alias));
typedef _Float16 h16x2 __attribute__((ext_vector_type(2)));
typedef _Float16 h16x8 __attribute__((ext_vector_type(8)));

#define MFMA(a,b,c) __builtin_amdgcn_mfma_f32_16x16x32_f16((a),(b),(c),0,0,0)

#define LBYTES 46080
#define HSTRIDE 304
// per-layer ws layout: A2 frag (x0.25) f=mf*4+kc @ f*1024 (32KB); W1-direct
// (x0.25) @ 32768: combo c=kc*4+g, 48B = {w1col0, w1col1, b1} h16x8 each;
// A3 kc (x0.1) @ (40+kc)*1024; smalls f32 @ 45056: [0..15]=PS [16..19]=PB
// [20..23]=0.1*b3 [24..151]=0.25*b2

__device__ __forceinline__ h16x2 pkrtz(float a, float b){
  auto t = __builtin_amdgcn_cvt_pkrtz(a, b);
  h16x2 r; __builtin_memcpy(&r, &t, 4); return r;
}
__device__ __forceinline__ unsigned pkh(float a, float b){
  auto t = __builtin_amdgcn_cvt_pkrtz(a, b);
  unsigned r; __builtin_memcpy(&r, &t, 4); return r;
}

// folded GELU: input xin = x/4 (weights prescaled). xq = clamp(xin, ±0.9375),
// y = xin * (2 + xq * D'(xq^2)), D' = 4*D (deg-9 odd overall, endpoint-exact).
__device__ __forceinline__ h16x2 gelu_pk4(h16x2 xin){
  const h16x2 CLO = {(_Float16)-0.9375f,    (_Float16)-0.9375f};
  const h16x2 CHI = {(_Float16)0.9375f,     (_Float16)0.9375f};
  const h16x2 E4  = {(_Float16)10.556124f,  (_Float16)10.556124f};
  const h16x2 E3  = {(_Float16)-27.682012f, (_Float16)-27.682012f};
  const h16x2 E2  = {(_Float16)28.723036f,  (_Float16)28.723036f};
  const h16x2 E1  = {(_Float16)-15.840256f, (_Float16)-15.840256f};
  const h16x2 E0  = {(_Float16)6.362512f,   (_Float16)6.362512f};
  const h16x2 H2  = {(_Float16)2.0f,        (_Float16)2.0f};
  h16x2 xq = __builtin_elementwise_max(xin, CLO);
  xq = __builtin_elementwise_min(xq, CHI);
  h16x2 t = xq * xq;
  h16x2 s = t*E4 + E3;
  s = s*t + E2;
  s = s*t + E1;
  s = s*t + E0;
  h16x2 inner = xq*s + H2;
  return xin * inner;
}

__device__ __forceinline__ void gelu4(const f32x4 c, unsigned& w0, unsigned& w1){
  h16x2 p0 = gelu_pk4(pkrtz(c[0], c[1]));
  h16x2 p1 = gelu_pk4(pkrtz(c[2], c[3]));
  __builtin_memcpy(&w0, &p0, 4);
  __builtin_memcpy(&w1, &p1, 4);
}

// ---------------- prepack (R22 + 0.25 prescale on W2/b2/W1d) ----------------
__global__ void prepack(const float* __restrict__ W1, const float* __restrict__ b1,
                        const float* __restrict__ W2, const float* __restrict__ b2,
                        const float* __restrict__ W3, const float* __restrict__ b3,
                        const float* __restrict__ gg, const float* __restrict__ off,
                        const float* __restrict__ Pm, unsigned char* __restrict__ ws)
{
  int t = blockIdx.x * 256 + threadIdx.x;
  if (t >= 8 * 45 * 64) return;
  int l    = t / (45 * 64);
  int rem  = t % (45 * 64);
  int f    = rem / 64;
  int lane = rem % 64;
  int p = lane & 15, g = lane >> 4;
  unsigned char* lb = ws + l * LBYTES;

  if (f < 32) {          // A2 fragment x0.25
    int mf = f >> 2, kc = f & 3;
    const float* rw = W2 + l*16384 + (16*mf + p)*128 + 32*kc + 8*g;
    f32x4 u0 = *(const f32x4*)rw;
    f32x4 u1 = *(const f32x4*)(rw + 4);
    i32x4 w;
    w[0] = (int)pkh(0.25f*u0[0], 0.25f*u0[1]); w[1] = (int)pkh(0.25f*u0[2], 0.25f*u0[3]);
    w[2] = (int)pkh(0.25f*u1[0], 0.25f*u1[1]); w[3] = (int)pkh(0.25f*u1[2], 0.25f*u1[3]);
    *(i32x4*)(lb + f*1024 + lane*16) = w;
  } else if (f == 32) {  // W1-direct x0.25: combo c=lane<16 (kc=c>>2, gq=c&3)
    if (lane < 16) {
      int kc = lane >> 2, gq = lane & 3;
      unsigned w0p[4], w1p[4], bbp[4];
      #pragma unroll
      for (int j2 = 0; j2 < 4; ++j2) {
        int n0 = 32*kc + 8*gq + 2*j2;
        int n1 = n0 + 1;
        w0p[j2] = pkh(0.25f*W1[l*256 + n0*2 + 0], 0.25f*W1[l*256 + n1*2 + 0]);
        w1p[j2] = pkh(0.25f*W1[l*256 + n0*2 + 1], 0.25f*W1[l*256 + n1*2 + 1]);
        bbp[j2] = pkh(0.25f*b1[l*128 + n0],       0.25f*b1[l*128 + n1]);
      }
      unsigned char* dst = lb + 32*1024 + lane*48;
      i32x4 a, b, c;
      #pragma unroll
      for (int q = 0; q < 4; ++q) { a[q]=(int)w0p[q]; b[q]=(int)w1p[q]; c[q]=(int)bbp[q]; }
      *(i32x4*)(dst)      = a;
      *(i32x4*)(dst + 16) = b;
      *(i32x4*)(dst + 32) = c;
    }
  } else if (f >= 40 && f < 44) {   // A3 x0.1 (validated)
    int kc = f - 40;
    i32x4 w = (i32x4){0,0,0,0};
    if (p < 4) {
      const float* rw = W3 + l*512 + p*128 + 8*g + 32*kc;
      f32x4 u0 = *(const f32x4*)(rw);
      f32x4 u1 = *(const f32x4*)(rw + 4);
      w[0] = (int)pkh(0.1f*u0[0], 0.1f*u0[1]); w[1] = (int)pkh(0.1f*u0[2], 0.1f*u0[3]);
      w[2] = (int)pkh(0.1f*u1[0], 0.1f*u1[1]); w[3] = (int)pkh(0.1f*u1[2], 0.1f*u1[3]);
    }
    *(i32x4*)(lb + f*1024 + lane*16) = w;
  } else if (f == 44) {  // smalls; b2 x0.25
    float* sm = (float*)(lb + 45056);
    if (lane < 16) {
      int j = lane & 3;
      float scl = 0.2f * log1pf(expf(0.5f * gg[l*4 + j]));
      sm[lane] = Pm[l*16 + lane] * scl;
    } else if (lane < 20) {
      int i = lane - 16; float acc = 0.f;
      #pragma unroll
      for (int j = 0; j < 4; ++j) acc += Pm[l*16 + i*4 + j] * off[l*4 + j];
      sm[16 + i] = acc;
    } else if (lane < 24) {
      sm[lane] = 0.1f * b3[l*4 + (lane - 20)];
    }
    sm[24 + lane]      = 0.25f * b2[l*128 + lane];
    sm[24 + 64 + lane] = 0.25f * b2[l*128 + 64 + lane];
  }
}

// ---------------- main kernel ----------------
__global__ __launch_bounds__(256, 3) void inn_main(
    const float* __restrict__ XYZ,
    const unsigned char* __restrict__ ws,
    float* __restrict__ outp)
{
  // per wave: h buffer 16*304=4864B + xs state 1024B = 5888B; 4 waves = 23552B
  __shared__ __align__(16) unsigned char lds[4*5888];

  const int tid  = threadIdx.x;
  const int wid  = tid >> 6;
  const int lane = tid & 63;
  const int p    = lane & 15;
  const int g    = lane >> 4;
  unsigned char* hb = lds + wid*5888;
  float* xs = (float*)(hb + 4864);
  const long base_pt = (long)blockIdx.x*256 + wid*64;
  const f32x4 z4 = {0.f,0.f,0.f,0.f};
  const unsigned loff = (unsigned)lane * 16u;

  if (lane < 16) {
    for (int s = 0; s < 4; ++s) {
      long pt = base_pt + s*16 + p;
      f32x4 v;
      v[0]=XYZ[pt*3+0]; v[1]=XYZ[pt*3+1]; v[2]=XYZ[pt*3+2]; v[3]=0.f;
      *(f32x4*)&xs[(s*16+p)*4] = v;
    }
  }
  MEMBAR();   // once, after state init

  for (int l = 0; l < 8; ++l) {
    const unsigned char* lb = ws + l * LBYTES;
    const float* sm = (const float*)(lb + 45056);
    f32x4 b3v = z4;
    if (g == 0) b3v = *(const f32x4*)(sm + 20);

    // ---- G1 direct (weights prescaled x0.25 -> feed gelu_pk4) ----
    h16x2 X0[4], X1[4];
    #pragma unroll
    for (int t = 0; t < 4; ++t) {
      f32x4 xv = *(const f32x4*)&xs[(t*16+p)*4];
      X0[t] = pkrtz(xv[0], xv[0]);
      X1[t] = pkrtz(xv[1], xv[1]);
    }
    h16x8 bfr1[4][4];   // [kc][slot]
    #pragma unroll
    for (int kc = 0; kc < 4; ++kc) {
      const unsigned char* wd = lb + 32*1024 + (kc*4 + g)*48;
      h16x2 w0p[4], w1p[4], bbp[4];
      __builtin_memcpy(w0p, wd,      16);
      __builtin_memcpy(w1p, wd + 16, 16);
      __builtin_memcpy(bbp, wd + 32, 16);
      #pragma unroll
      for (int t = 0; t < 4; ++t) {
        h16x2 hp[4];
        #pragma unroll
        for (int j2 = 0; j2 < 4; ++j2) {
          h16x2 v = w0p[j2]*X0[t] + w1p[j2]*X1[t] + bbp[j2];
          hp[j2] = gelu_pk4(v);
        }
        __builtin_memcpy(&bfr1[kc][t], hp, 16);
      }
    }

    // ---- G2+G3 fused per mf-pair (A2/b2 prescaled; gelu_pk4 in gelu4) ----
    f32x4 c3[4];
    #pragma unroll
    for (int t = 0; t < 4; ++t) c3[t] = b3v;
    #pragma unroll
    for (int mfp = 0; mfp < 4; ++mfp) {
      f32x4 bv0 = *(const f32x4*)(sm + 24 + 16*(2*mfp)   + 4*g);
      f32x4 bv1 = *(const f32x4*)(sm + 24 + 16*(2*mfp+1) + 4*g);
      f32x4 c2a[4], c2b[4];
      #pragma unroll
      for (int t = 0; t < 4; ++t) { c2a[t] = bv0; c2b[t] = bv1; }
      #pragma unroll
      for (int kc = 0; kc < 4; ++kc) {
        h16x8 af0 = *(const h16x8*)(lb + ((2*mfp)*4   + kc)*1024 + loff);
        h16x8 af1 = *(const h16x8*)(lb + ((2*mfp+1)*4 + kc)*1024 + loff);
        #pragma unroll
        for (int t = 0; t < 4; ++t) {
          c2a[t] = MFMA(af0, bfr1[kc][t], c2a[t]);
          c2b[t] = MFMA(af1, bfr1[kc][t], c2b[t]);
        }
      }
      h16x8 a3 = *(const h16x8*)(lb + (40 + mfp)*1024 + loff);
      #pragma unroll
      for (int t = 0; t < 4; ++t) {
        i32x4 w; unsigned w0,w1,w2,w3;
        gelu4(c2a[t], w0, w1); gelu4(c2b[t], w2, w3);
        w[0]=(int)w0; w[1]=(int)w1; w[2]=(int)w2; w[3]=(int)w3;
        *(i32x4*)(hb + p*HSTRIDE + (4*t + g)*16) = w;
      }
      #pragma unroll
      for (int t = 0; t < 4; ++t) {
        const unsigned char* ra = hb + p*HSTRIDE + (4*t + 2*(g & 1))*16 + (g >> 1)*8;
        s16x4 lo = *(const s16x4*)(ra);
        s16x4 hi = *(const s16x4*)(ra + 16);
        h16x8 b;
        __builtin_memcpy(&b, &lo, 8);
        __builtin_memcpy(((char*)&b)+8, &hi, 8);
        c3[t] = MFMA(a3, b, c3[t]);
      }
    }

    // ---- tail: gather all slots' a_i, then each lane computes slot t=g ----
    f32x4 ps0 = *(const f32x4*)(sm + 0);
    f32x4 ps1 = *(const f32x4*)(sm + 4);
    f32x4 ps2 = *(const f32x4*)(sm + 8);
    f32x4 ps3 = *(const f32x4*)(sm + 12);
    f32x4 pb  = *(const f32x4*)(sm + 16);
    int addr = p << 2;
    f32x4 av[4];   // av[t][i] = a_i for slot t (static indexing only)
    #pragma unroll
    for (int t = 0; t < 4; ++t) {
      #pragma unroll
      for (int i = 0; i < 4; ++i)
        av[t][i] = __int_as_float(__builtin_amdgcn_ds_bpermute(addr, __float_as_int(c3[t][i])));
    }
    // cndmask-select slot g (all static indices)
    f32x4 as;
    #pragma unroll
    for (int i = 0; i < 4; ++i) {
      float v01 = (g & 1) ? av[1][i] : av[0][i];
      float v23 = (g & 1) ? av[3][i] : av[2][i];
      as[i] = (g & 2) ? v23 : v01;
    }
    {
      f32x4 xv = *(const f32x4*)&xs[(g*16+p)*4];
      float t0 = __builtin_amdgcn_rcpf(1.f + __builtin_amdgcn_exp2f(2.8853901f * as[0]));
      float t1 = __builtin_amdgcn_rcpf(1.f + __builtin_amdgcn_exp2f(2.8853901f * as[1]));
      float e0 = __builtin_amdgcn_exp2f(__builtin_fmaf(-5.7707802f, t0, 2.8853901f));
      float e1 = __builtin_amdgcn_exp2f(__builtin_fmaf(-5.7707802f, t1, 2.8853901f));
      float v2 = __builtin_fmaf(xv[2], e0, as[2]);
      float v3 = __builtin_fmaf(xv[3], e1, as[3]);
      f32x4 y;
      y[0] = __builtin_fmaf(ps0[0], xv[0], __builtin_fmaf(ps0[1], xv[1],
             __builtin_fmaf(ps0[2], v2, __builtin_fmaf(ps0[3], v3, pb[0]))));
      y[1] = __builtin_fmaf(ps1[0], xv[0], __builtin_fmaf(ps1[1], xv[1],
             __builtin_fmaf(ps1[2], v2, __builtin_fmaf(ps1[3], v3, pb[1]))));
      y[2] = __builtin_fmaf(ps2[0], xv[0], __builtin_fmaf(ps2[1], xv[1],
             __builtin_fmaf(ps2[2], v2, __builtin_fmaf(ps2[3], v3, pb[2]))));
      y[3] = __builtin_fmaf(ps3[0], xv[0], __builtin_fmaf(ps3[1], xv[1],
             __builtin_fmaf(ps3[2], v2, __builtin_fmaf(ps3[3], v3, pb[3]))));
      *(f32x4*)&xs[(g*16+p)*4] = y;   // 64 lanes -> 64 distinct slots/points
    }
    MEMBAR();   // xs writes ordered before next layer's xs reads
  }

  if (lane < 16) {
    for (int s = 0; s < 4; ++s) {
      long pt = base_pt + s*16 + p;
      f32x4 xv = *(const f32x4*)&xs[(s*16+p)*4];
      outp[pt*3+0] = xv[0];
      outp[pt*3+1] = xv[1];
      outp[pt*3+2] = xv[2];
    }
  }
}

extern "C" void kernel_launch(void* const* d_in, const int* in_sizes, int n_in,
                              void* d_out, int out_size, void* d_ws, size_t ws_size,
                              hipStream_t stream)
{
  const float* XYZ = (const float*)d_in[0];
  const float* W1  = (const float*)d_in[1];
  const float* b1  = (const float*)d_in[2];
  const float* W2  = (const float*)d_in[3];
  const float* b2  = (const float*)d_in[4];
  const float* W3  = (const float*)d_in[5];
  const float* b3  = (const float*)d_in[6];
  const float* g   = (const float*)d_in[7];
  const float* off = (const float*)d_in[8];
  const float* P   = (const float*)d_in[9];
  unsigned char* ws = (unsigned char*)d_ws;

  prepack<<<90, 256, 0, stream>>>(W1, b1, W2, b2, W3, b3, g, off, P, ws);

  int Bn = in_sizes[0] / 3;          // 524288
  int nblocks = Bn / 256;            // 2048 exact
  inn_main<<<nblocks, 256, 0, stream>>>(XYZ, ws, (float*)d_out);
}